// Round 21
// baseline (3154.733 us; speedup 1.0000x reference)
//
#include <hip/hip_runtime.h>
#include <hip/hip_bf16.h>

#define NPX 6912   // 96*72
typedef unsigned long long u64;
typedef int i32x4 __attribute__((ext_vector_type(4)));

__device__ __forceinline__ int ea_from_bits(u64 bits){
    double m = __longlong_as_double((long long)bits);
    if (!(m > 0.0)) return 0;
    return ilogb(m) + 1;
}
// balanced radix-256 digits of round(a*2^sh): q = ((d0*256+d1)*256+d2)*256+d3 exactly
__device__ __forceinline__ void digits4(double a, int sh, int& d0, int& d1, int& d2, int& d3){
    long long q = __double2ll_rn(ldexp(a, sh));
    d3 = (int)(((q + 128) & 255) - 128); q = (q - d3) >> 8;
    d2 = (int)(((q + 128) & 255) - 128); q = (q - d2) >> 8;
    d1 = (int)(((q + 128) & 255) - 128);
    d0 = (int)((q - d1) >> 8);
}
// bijective XCD swizzle (requires nwg % 8 == 0)
__device__ __forceinline__ int xcd_swz(int bid, int nwg){
    return (bid & 7) * (nwg >> 3) + (bid >> 3);
}

// ---------------- diff = y - x (f64) + absmax -> maxbuf[slot] ----------------
__global__ __launch_bounds__(256) void diff_kd(const float* __restrict__ x,
    const float* __restrict__ y, double* __restrict__ d, int n,
    u64* maxbuf, int slot){
    int i = blockIdx.x*256 + threadIdx.x;
    double m = 0.0;
    if (i < n){ double v = (double)y[i] - (double)x[i]; d[i] = v; m = fabs(v); }
    #pragma unroll
    for (int o=32;o;o>>=1) m = fmax(m, __shfl_down(m,o));
    __shared__ double W[4];
    if ((threadIdx.x&63)==0) W[threadIdx.x>>6]=m;
    __syncthreads();
    if (threadIdx.x==0){
        m = fmax(fmax(W[0],W[1]),fmax(W[2],W[3]));
        atomicMax(maxbuf+slot,(u64)__double_as_longlong(m));
    }
}

// ---------------- 1x1 conv 17->128 + bn, fp64 ----------------
__global__ __launch_bounds__(256) void conv1x1_d(const double* __restrict__ in,
    const float* __restrict__ wgt, const float* __restrict__ scale,
    const float* __restrict__ shift, double* __restrict__ out){
    __shared__ float Ws[17*128];
    const int t = threadIdx.x;
    for (int e=t; e<17*128; e+=256){
        int ic = e >> 7, oc = e & 127;
        Ws[e] = wgt[oc*17 + ic];
    }
    __syncthreads();
    const int pxl = t & 31, ocg = t >> 5;
    const int p = blockIdx.x*32 + pxl;
    const int b = p / NPX, pi = p - b*NPX;
    double acc[16];
    #pragma unroll
    for (int j=0;j<16;j++) acc[j]=0.0;
    const double* inb = in + (size_t)b*17*NPX + pi;
    #pragma unroll
    for (int ic=0;ic<17;ic++){
        const double a = inb[(size_t)ic*NPX];
        #pragma unroll
        for (int j=0;j<16;j++) acc[j] = fma(a, (double)Ws[(ic<<7)+(ocg<<4)+j], acc[j]);
    }
    #pragma unroll
    for (int j=0;j<16;j++){
        const int oc = (ocg<<4)+j;
        out[((size_t)b*128+oc)*NPX + pi] = fma(acc[j], (double)scale[oc], (double)shift[oc]);
    }
}

// ---------------- activation decompose: f64 [2][128][NPX] -> i8 [4][2][PS][128] ----
// grid 864 (2b x 432 sixteen-px groups); 16-px rows -> 128B read segments (G2/G13)
__global__ __launch_bounds__(256) void adecomp_k(const double* __restrict__ src,
    signed char* __restrict__ dst, const u64* __restrict__ maxbuf, int slot,
    int PS, int PW, int PB)
{
    __shared__ signed char L[4][16][128];  // 8 KB
    const int t = threadIdx.x;
    const int b = blockIdx.x / 432, px0 = (blockIdx.x % 432) * 16;
    const int sh = 30 - ea_from_bits(maxbuf[slot]);
    const int tp = t & 15, tc = t >> 4;    // 16 px x 16 c-lanes
    #pragma unroll
    for (int i=0;i<8;i++){
        const int c = tc + i*16;
        double a = src[((size_t)b*128 + c)*NPX + px0 + tp];
        int d0,d1,d2,d3; digits4(a, sh, d0,d1,d2,d3);
        L[0][tp][c] = (signed char)d0;
        L[1][tp][c] = (signed char)d1;
        L[2][tp][c] = (signed char)d2;
        L[3][tp][c] = (signed char)d3;
    }
    __syncthreads();
    #pragma unroll
    for (int i=0;i<2;i++){
        const int e = t + (i<<8);          // [0,512) 16B units: l(2b) px(4b) chunk(3b)
        const int l = e >> 7, px = (e >> 3) & 15, chunk = e & 7;
        const int pix = px0 + px, yy = pix/72, xx = pix - yy*72;
        const size_t po = ((size_t)(l*2+b)*PS + (size_t)(yy+PB)*PW + (xx+PB))*128 + chunk*16;
        *(uint4*)(dst+po) = *(const uint4*)(&L[l][px][chunk*16]);
    }
}

// ---------------- diff decompose: f64 [2][17][NPX] -> i8 [4][2][7448][64] ----
__global__ __launch_bounds__(256) void adecomp17_k(const double* __restrict__ src,
    signed char* __restrict__ dst, const u64* __restrict__ maxbuf, int slot)
{
    __shared__ signed char L[4][16][64];    // 4 KB
    const int t = threadIdx.x;
    const int b = blockIdx.x / 432, px0 = (blockIdx.x % 432) * 16;
    const int sh = 30 - ea_from_bits(maxbuf[slot]);
    uint4 z = {0,0,0,0};
    *(uint4*)(((signed char*)L) + t*16) = z;   // zero all 4096 B
    __syncthreads();
    const int tp = t & 15, tc = t >> 4;
    #pragma unroll
    for (int i=0;i<2;i++){
        const int c = tc + i*16;
        if (c < 17){
            double a = src[((size_t)b*17 + c)*NPX + px0 + tp];
            int d0,d1,d2,d3; digits4(a, sh, d0,d1,d2,d3);
            L[0][tp][c] = (signed char)d0;
            L[1][tp][c] = (signed char)d1;
            L[2][tp][c] = (signed char)d2;
            L[3][tp][c] = (signed char)d3;
        }
    }
    __syncthreads();
    const int l = t >> 6, wpx = (t >> 2) & 15, chunk = t & 3;
    const int pix = px0 + wpx, yy = pix/72, xx = pix - yy*72;
    const size_t po = ((size_t)(l*2+b)*7448 + (size_t)(yy+1)*76 + (xx+1))*64 + chunk*16;
    *(uint4*)(dst+po) = *(const uint4*)(&L[l][wpx][chunk*16]);
}

// ------- weight prepack: fp32 [ocw][ICw][9] -> i8 per-tap 4*32*ICpad units, swizzled ----
// unit layout: [l][o32][xk][16]; ICpad=128: xk = k16 ^ (o32&7); ICpad=64: xk = k16 ^ ((o32>>1)&3)
__device__ __forceinline__ void wprep_body(const float* src,
    signed char* Bpk, int* Eb, int oc, int t,
    int ocw, int ICw, int ICpad, int OCpad)
{
    const int NW = ICw*9;
    float m = 0.f;
    if (oc < ocw)
        for (int e=t;e<NW;e+=64) m = fmaxf(m, fabsf(src[(size_t)oc*NW+e]));
    #pragma unroll
    for (int o=32;o;o>>=1) m = fmaxf(m, __shfl_down(m,o));
    m = __shfl(m, 0);
    const int Ebv = (m>0.f)?(ilogbf(m)+1):0;
    if (t==0) Eb[oc]=Ebv;
    const int sh = 30 - Ebv;
    const int nc16 = ICpad >> 4;
    const int PERSTEP = 4*32*ICpad;
    const size_t perOt = (size_t)9*PERSTEP;
    const int ot = oc >> 5, o32 = oc & 31;
    const int nchunks = nc16*9;
    for (int mci=t; mci<nchunks; mci+=64){
        const int ic16 = mci % nc16, tap = mci / nc16;
        const int xk = (ICpad==128) ? (ic16 ^ (o32 & 7)) : (ic16 ^ ((o32>>1) & 3));
        __align__(16) signed char dig[4][16];
        #pragma unroll
        for (int j=0;j<16;j++){
            const int ic = ic16*16+j;
            float w = (oc<ocw && ic<ICw) ? src[((size_t)oc*ICw+ic)*9+tap] : 0.f;
            int d0,d1,d2,d3; digits4((double)w, sh, d0,d1,d2,d3);
            dig[0][j]=(signed char)d0;
            dig[1][j]=(signed char)d1;
            dig[2][j]=(signed char)d2;
            dig[3][j]=(signed char)d3;
        }
        const size_t base = (size_t)ot*perOt + (size_t)tap*PERSTEP
                          + (size_t)o32*ICpad + (xk<<4);
        #pragma unroll
        for (int l=0;l<4;l++)
            *(uint4*)(Bpk + base + (size_t)l*32*ICpad) = *(const uint4*)(&dig[l][0]);
    }
}

__global__ __launch_bounds__(64) void wprep_k(const float* __restrict__ wgt,
    signed char* __restrict__ Bpk, int* __restrict__ Eb,
    int ocw, int ICw, int ICpad, int OCpad)
{
    wprep_body(wgt, Bpk, Eb, blockIdx.x, threadIdx.x, ocw, ICw, ICpad, OCpad);
}

// all 45 layers in one launch. slots: 0=b0w1(IC17,pad64) 1=b0w2 2+2i=bw1[i] 3+2i=bw2[i] 40+d=offw[d]
__global__ __launch_bounds__(64) void wprep_all(
    const float* __restrict__ b0w1, const float* __restrict__ b0w2,
    const float* __restrict__ bw1, const float* __restrict__ bw2,
    const float* __restrict__ offw,
    signed char* __restrict__ BpkAll, int* __restrict__ EbAll)
{
    const int slot = blockIdx.y;
    const float* src; int ocw, ICw, ICpad, OCpad;
    signed char* Bpk;
    if (slot < 40){
        Bpk = BpkAll + (size_t)slot * 589824;
        ocw = 128; OCpad = 128;
        if (slot == 0){ src=b0w1; ICw=17; ICpad=64; }
        else if (slot == 1){ src=b0w2; ICw=128; ICpad=128; }
        else { int i=(slot-2)>>1; src = (((slot-2)&1)? bw2:bw1) + (size_t)i*147456; ICw=128; ICpad=128; }
    } else {
        Bpk = BpkAll + 40ull*589824 + (size_t)(slot-40)*1474560;
        src = offw + (size_t)(slot-40)*352512; ocw=306; ICw=128; ICpad=128; OCpad=320;
    }
    if ((int)blockIdx.x >= OCpad) return;
    wprep_body(src, Bpk, EbAll + slot*320, blockIdx.x, threadIdx.x, ocw, ICw, ICpad, OCpad);
}

// ---- exact limb-MFMA(i8) trunk conv: 2-wave blocks, 32px x 32oc per wave (R19 cfg) ----
#define MFI(A,B,C) __builtin_amdgcn_mfma_i32_16x16x64_i8(A,B,C,0,0,0)

template<int MODE, int NCC>
__global__ __launch_bounds__(128, 2) void convL(
    const signed char* __restrict__ inL, int PS, int PW, int PB, int dil,
    const signed char* __restrict__ Bpk, const int* __restrict__ Eb,
    int OCw, int OCT,
    const u64* __restrict__ maxbuf, int easlot,
    const float* __restrict__ scale, const float* __restrict__ shift,
    const double* res, void* outp, u64* maxout, int moslot)
{
    constexpr int CC = NCC*64;
    constexpr int NSTEP = 9;
    constexpr int PERSTEP = 4*32*CC;          // 8KB (NCC=1) / 16KB (NCC=2)
    constexpr int LSTR = 32*CC;
    constexpr int NCHUNK = PERSTEP/2048;      // per-thread 16B chunks (128 thr)
    __shared__ signed char Bs[2][PERSTEP];    // 16/32 KB
    const int t = threadIdx.x;
    const int w = t >> 6, lane = t & 63;
    const int ocl = lane & 15, rq = lane >> 4;
    const int lb = xcd_swz(blockIdx.x, gridDim.x);
    const int oct = lb % OCT, pxt = lb / OCT;
    const int b = pxt / 108, px0 = (pxt - b*108) * 64 + w*32;
    const int oc0 = oct * 32;

    long long aBase[2];
    #pragma unroll
    for (int mt=0; mt<2; mt++){
        const int px = px0 + mt*16 + ocl;
        const int sy = px/72, sx = px - sy*72;
        aBase[mt] = ((long long)b*PS + (long long)(sy+PB)*PW + (sx+PB))*CC + rq*16;
    }
    const long long pStr = (long long)2*PS*CC;
    const signed char* Bsl = Bpk + (size_t)oct * ((size_t)NSTEP*PERSTEP);

    i32x4 c0[2][2], c1[2][2], c2[2][2], c3[2][2];   // [mt][nt]
    #pragma unroll
    for (int i=0;i<2;i++)
      #pragma unroll
      for (int j=0;j<2;j++){
        c0[i][j]=(i32x4)(0); c1[i][j]=(i32x4)(0);
        c2[i][j]=(i32x4)(0); c3[i][j]=(i32x4)(0);
      }

    const int Ea = ea_from_bits(maxbuf[easlot]);

    auto STAGE = [&](int s, int buf){
        const signed char* src = Bsl + (size_t)s*PERSTEP + w*1024 + (lane<<4);
        #pragma unroll
        for (int j=0;j<NCHUNK;j++)
            __builtin_amdgcn_global_load_lds((const unsigned int*)(src + j*2048),
                                             (unsigned int*)(&Bs[buf][j*2048 + w*1024]), 16, 0, 0);
    };

    STAGE(0, 0);
    __builtin_amdgcn_sched_barrier(0);

    for (int s=0; s<NSTEP; s++){
        if (s == 0)           asm volatile("s_waitcnt vmcnt(0)  lgkmcnt(0)" ::: "memory");
        else if (NCC==2)      asm volatile("s_waitcnt vmcnt(16) lgkmcnt(0)" ::: "memory");
        else                  asm volatile("s_waitcnt vmcnt(8)  lgkmcnt(0)" ::: "memory");
        __builtin_amdgcn_s_barrier();
        __builtin_amdgcn_sched_barrier(0);

        if (s+1 < NSTEP) STAGE(s+1, (s+1)%2);

        const int ty = s/3, tx = s - ty*3;
        const long long dofs = ((long long)(ty-1)*PW + (tx-1)) * dil * CC;
        const signed char* bsb = &Bs[s%2][0];

        i32x4 af[NCC][2][4];    // [icc][mt][l]
        #pragma unroll
        for (int icc=0; icc<NCC; icc++)
          #pragma unroll
          for (int mt=0; mt<2; mt++)
            #pragma unroll
            for (int l=0;l<4;l++)
                af[icc][mt][l] = *(const i32x4*)(inL + (aBase[mt] + dofs + icc*64 + (long long)l*pStr));

        i32x4 bfr[NCC][2][4];   // [icc][nt][l]
        #pragma unroll
        for (int icc=0; icc<NCC; icc++)
          #pragma unroll
          for (int nt=0; nt<2; nt++){
            const int o32 = nt*16 + ocl;
            const int xk = (NCC==2) ? ((icc*4+rq) ^ (o32 & 7)) : (rq ^ ((o32>>1) & 3));
            const int off = o32*CC + (xk<<4);
            #pragma unroll
            for (int l=0;l<4;l++)
                bfr[icc][nt][l] = *(const i32x4*)(bsb + l*LSTR + off);
          }

        __builtin_amdgcn_s_setprio(1);
        #pragma unroll
        for (int icc=0; icc<NCC; icc++)
          #pragma unroll
          for (int nt=0; nt<2; nt++)
            #pragma unroll
            for (int mt=0; mt<2; mt++){
              c0[mt][nt]=MFI(af[icc][mt][0],bfr[icc][nt][0],c0[mt][nt]);
              c1[mt][nt]=MFI(af[icc][mt][0],bfr[icc][nt][1],c1[mt][nt]);
              c1[mt][nt]=MFI(af[icc][mt][1],bfr[icc][nt][0],c1[mt][nt]);
              c2[mt][nt]=MFI(af[icc][mt][0],bfr[icc][nt][2],c2[mt][nt]);
              c2[mt][nt]=MFI(af[icc][mt][1],bfr[icc][nt][1],c2[mt][nt]);
              c2[mt][nt]=MFI(af[icc][mt][2],bfr[icc][nt][0],c2[mt][nt]);
              c3[mt][nt]=MFI(af[icc][mt][0],bfr[icc][nt][3],c3[mt][nt]);
              c3[mt][nt]=MFI(af[icc][mt][1],bfr[icc][nt][2],c3[mt][nt]);
              c3[mt][nt]=MFI(af[icc][mt][2],bfr[icc][nt][1],c3[mt][nt]);
              c3[mt][nt]=MFI(af[icc][mt][3],bfr[icc][nt][0],c3[mt][nt]);
            }
        __builtin_amdgcn_s_setprio(0);
    }

    if (MODE != 2){
        double mx = 0.0;
        #pragma unroll
        for (int nt=0;nt<2;nt++){
            const int oc = oc0 + nt*16 + ocl;
            const int ex = Ea + Eb[oc] - 36;
            const double sc = (double)scale[oc], sf = (double)shift[oc];
            #pragma unroll
            for (int mt=0;mt<2;mt++){
                const size_t ob = ((size_t)(b*128+oc))*NPX + px0 + mt*16 + rq*4;
                double4 rv;
                if (MODE==1) rv = *(const double4*)(res+ob);
                double vv[4];
                #pragma unroll
                for (int v=0;v<4;v++){
                    const long long comb = ((long long)c0[mt][nt][v]<<24) + ((long long)c1[mt][nt][v]<<16)
                                         + ((long long)c2[mt][nt][v]<<8)  +  (long long)c3[mt][nt][v];
                    double dv = fma(ldexp((double)comb, ex), sc, sf);
                    if (MODE==1) dv += (&rv.x)[v];
                    dv = dv>0.0 ? dv : 0.0;
                    vv[v]=dv; mx = fmax(mx,dv);
                }
                double4 st = {vv[0],vv[1],vv[2],vv[3]};
                *(double4*)((double*)outp+ob) = st;
            }
        }
        #pragma unroll
        for (int o=32;o;o>>=1) mx = fmax(mx,__shfl_down(mx,o));
        if (lane==0) atomicMax(maxout+moslot,(u64)__double_as_longlong(mx));
    } else {
        #pragma unroll
        for (int nt=0;nt<2;nt++){
            const int oc = oc0 + nt*16 + ocl;
            if (oc < OCw){
                const int ex = Ea + Eb[oc] - 36;
                #pragma unroll
                for (int mt=0;mt<2;mt++){
                    const size_t ob = ((size_t)b*OCw+oc)*NPX + px0 + mt*16 + rq*4;
                    float4 st;
                    #pragma unroll
                    for (int v=0;v<4;v++){
                        const long long comb = ((long long)c0[mt][nt][v]<<24) + ((long long)c1[mt][nt][v]<<16)
                                             + ((long long)c2[mt][nt][v]<<8)  +  (long long)c3[mt][nt][v];
                        (&st.x)[v] = (float)ldexp((double)comb, ex);
                    }
                    *(float4*)((float*)outp+ob) = st;
                }
            }
        }
    }
}

// ---- FUSED offset conv: 16px x 32oc per wave, all 5 dilations (R17/R18 cfg, verbatim) ----
__global__ __launch_bounds__(256, 2) void convLo(
    const signed char* __restrict__ inL, int PS, int PW, int PB,
    const signed char* __restrict__ BpkAll, const int* __restrict__ EbAll,
    const u64* __restrict__ maxbuf, int easlot, float* __restrict__ outAll)
{
    constexpr int CC = 128;
    constexpr int NSTEP = 9;
    constexpr int PERSTEP = 4*32*CC;          // 16KB
    constexpr int LSTR = 32*CC;
    __shared__ signed char Bs[2][PERSTEP];    // 32 KB
    const int t = threadIdx.x;
    const int w = t >> 6, lane = t & 63;
    const int ocl = lane & 15, rq = lane >> 4;
    const int lb = xcd_swz(blockIdx.x, gridDim.x);
    const int d = lb / 2160, r = lb - d*2160;
    const int dil = d ? 6*d : 3;
    const int oct = r % 10, pxt = r / 10;
    const int b = pxt / 108, px0 = (pxt - b*108) * 64 + w*16;
    const int oc0 = oct * 32;
    const int* Eb = EbAll + d*320;
    float* outp = outAll + (size_t)d*4230144;

    const int px = px0 + ocl;
    const int sy = px/72, sx = px - sy*72;
    const long long aBase = ((long long)b*PS + (long long)(sy+PB)*PW + (sx+PB))*CC + rq*16;
    const long long pStr = (long long)2*PS*CC;
    const signed char* Bsl = BpkAll + (size_t)d*1474560 + (size_t)oct * ((size_t)NSTEP*PERSTEP);

    i32x4 c0[2], c1[2], c2[2], c3[2];
    #pragma unroll
    for (int j=0;j<2;j++){
        c0[j]=(i32x4)(0); c1[j]=(i32x4)(0);
        c2[j]=(i32x4)(0); c3[j]=(i32x4)(0);
    }

    const int Ea = ea_from_bits(maxbuf[easlot]);

    auto STAGE = [&](int s, int buf){
        const signed char* src = Bsl + (size_t)s*PERSTEP + w*1024 + (lane<<4);
        #pragma unroll
        for (int j=0;j<PERSTEP/4096;j++)
            __builtin_amdgcn_global_load_lds((const unsigned int*)(src + j*4096),
                                             (unsigned int*)(&Bs[buf][j*4096 + w*1024]), 16, 0, 0);
    };

    STAGE(0, 0);
    __builtin_amdgcn_sched_barrier(0);

    for (int s=0; s<NSTEP; s++){
        if (s == 0) asm volatile("s_waitcnt vmcnt(0) lgkmcnt(0)" ::: "memory");
        else        asm volatile("s_waitcnt vmcnt(8) lgkmcnt(0)" ::: "memory");
        __builtin_amdgcn_s_barrier();
        __builtin_amdgcn_sched_barrier(0);

        if (s+1 < NSTEP) STAGE(s+1, (s+1)%2);

        const int ty = s/3, tx = s - ty*3;
        const long long dofs = ((long long)(ty-1)*PW + (tx-1)) * dil * CC;
        const signed char* bsb = &Bs[s%2][0];

        i32x4 af[2][4];    // [icc][l]
        #pragma unroll
        for (int icc=0; icc<2; icc++)
          #pragma unroll
          for (int l=0;l<4;l++)
            af[icc][l] = *(const i32x4*)(inL + (aBase + dofs + icc*64 + (long long)l*pStr));

        i32x4 bfr[2][2][4];   // [icc][nt][l]
        #pragma unroll
        for (int icc=0; icc<2; icc++)
          #pragma unroll
          for (int nt=0; nt<2; nt++){
            const int o32 = nt*16 + ocl;
            const int xk = (icc*4+rq) ^ (o32 & 7);
            const int off = o32*CC + (xk<<4);
            #pragma unroll
            for (int l=0;l<4;l++)
                bfr[icc][nt][l] = *(const i32x4*)(bsb + l*LSTR + off);
          }

        __builtin_amdgcn_s_setprio(1);
        #pragma unroll
        for (int icc=0; icc<2; icc++)
          #pragma unroll
          for (int nt=0; nt<2; nt++){
            c0[nt]=MFI(af[icc][0],bfr[icc][nt][0],c0[nt]);
            c1[nt]=MFI(af[icc][0],bfr[icc][nt][1],c1[nt]);
            c1[nt]=MFI(af[icc][1],bfr[icc][nt][0],c1[nt]);
            c2[nt]=MFI(af[icc][0],bfr[icc][nt][2],c2[nt]);
            c2[nt]=MFI(af[icc][1],bfr[icc][nt][1],c2[nt]);
            c2[nt]=MFI(af[icc][2],bfr[icc][nt][0],c2[nt]);
            c3[nt]=MFI(af[icc][0],bfr[icc][nt][3],c3[nt]);
            c3[nt]=MFI(af[icc][1],bfr[icc][nt][2],c3[nt]);
            c3[nt]=MFI(af[icc][2],bfr[icc][nt][1],c3[nt]);
            c3[nt]=MFI(af[icc][3],bfr[icc][nt][0],c3[nt]);
          }
        __builtin_amdgcn_s_setprio(0);
    }

    #pragma unroll
    for (int nt=0;nt<2;nt++){
        const int oc = oc0 + nt*16 + ocl;
        if (oc < 306){
            const int ex = Ea + Eb[oc] - 36;
            const size_t ob = ((size_t)b*306+oc)*NPX + px0 + rq*4;
            float4 st;
            #pragma unroll
            for (int v=0;v<4;v++){
                const long long comb = ((long long)c0[nt][v]<<24) + ((long long)c1[nt][v]<<16)
                                     + ((long long)c2[nt][v]<<8)  +  (long long)c3[nt][v];
                (&st.x)[v] = (float)ldexp((double)comb, ex);
            }
            *(float4*)(outp+ob) = st;
        }
    }
}

// ------ deformable conv body, fp64, 16px x 16 c-groups + LDS reduce, 0.2x into out ----
__device__ __forceinline__ void deform_body(
    const float* xin, const float* off, const float* dcw, float* out, int dil,
    int blk, int t)
{
    __shared__ float Wsm[17*153];
    __shared__ double R[16][16][17];      // 34.8 KB
    for (int e=t;e<17*153;e+=256) Wsm[e] = dcw[e];
    __syncthreads();
    const int pxl = t & 15, cg = t >> 4;
    const int p = blk*16 + pxl;           // 864*16 = 13824
    const int b = p / NPX, pi = p - b*NPX;
    const int yy = pi/72, xx = pi - yy*72;
    const float* img = xin + (size_t)b*17*NPX;
    const float* ob  = off + (size_t)b*306*NPX + pi;
    const int cbeg = (cg==0) ? 0 : (cg+1);
    const int cnt  = (cg==0) ? 2 : 1;
    double acc[17];
    #pragma unroll
    for (int o=0;o<17;o++) acc[o]=0.0;
    for (int ci=0; ci<cnt; ci++){
        const int c = cbeg + ci;
        const float* im = img + c*NPX;
        #pragma unroll
        for (int k=0;k<9;k++){
            const double dy = (double)ob[((c*9+k)*2+0)*NPX];
            const double dx = (double)ob[((c*9+k)*2+1)*NPX];
            const double py  = (double)yy + dy + (double)((k/3-1)*dil);
            const double pxd = (double)xx + dx + (double)((k%3-1)*dil);
            const double y0f = floor(py), x0f = floor(pxd);
            const double wy = py - y0f, wx = pxd - x0f;
            const int y0 = (int)fmax(fmin(y0f, 97.0), -2.0);
            const int x0 = (int)fmax(fmin(x0f, 73.0), -2.0);
            const bool yv0 = (y0   >= 0) && (y0   < 96);
            const bool yv1 = (y0+1 >= 0) && (y0+1 < 96);
            const bool xv0 = (x0   >= 0) && (x0   < 72);
            const bool xv1 = (x0+1 >= 0) && (x0+1 < 72);
            const int yc0 = min(max(y0  ,0),95), yc1 = min(max(y0+1,0),95);
            const int xc0 = min(max(x0  ,0),71), xc1 = min(max(x0+1,0),71);
            const double v00 = (yv0&&xv0) ? (double)im[yc0*72+xc0] : 0.0;
            const double v01 = (yv0&&xv1) ? (double)im[yc0*72+xc1] : 0.0;
            const double v10 = (yv1&&xv0) ? (double)im[yc1*72+xc0] : 0.0;
            const double v11 = (yv1&&xv1) ? (double)im[yc1*72+xc1] : 0.0;
            const double s = v00*(1.0-wy)*(1.0-wx) + v01*(1.0-wy)*wx
                           + v10*wy*(1.0-wx)       + v11*wy*wx;
            const int ck = c*9+k;
            #pragma unroll
            for (int o=0;o<17;o++)
                acc[o] = fma((double)Wsm[o*153+ck], s, acc[o]);
        }
    }
    #pragma unroll
    for (int o=0;o<17;o++) R[cg][pxl][o] = acc[o];
    __syncthreads();
    const int og = cg;
    const int obeg = (og==0) ? 0 : (og+1);
    const int ocnt = (og==0) ? 2 : 1;
    for (int oi=0; oi<ocnt; oi++){
        const int o = obeg + oi;
        double s = 0.0;
        #pragma unroll
        for (int g=0; g<16; g++) s += R[g][pxl][o];
        atomicAdd(out + ((size_t)b*17+o)*NPX + pi, (float)(0.2*s));
    }
}

__global__ __launch_bounds__(256) void deform_kd(
    const float* __restrict__ xin, const float* __restrict__ off,
    const float* __restrict__ dcw, float* out, int dil)
{
    deform_body(xin, off, dcw, out, dil, blockIdx.x, threadIdx.x);
}

// fused: grid 4320 = 5 dil x 864
__global__ __launch_bounds__(256) void deform_all(
    const float* __restrict__ xin, const float* __restrict__ offAll,
    const float* __restrict__ dcwAll, float* out)
{
    const int d = blockIdx.x / 864, blk = blockIdx.x - d*864;
    const int dil = d ? 6*d : 3;
    deform_body(xin, offAll + (size_t)d*4230144, dcwAll + d*2601, out, dil,
                blk, threadIdx.x);
}

extern "C" void kernel_launch(void* const* d_in, const int* in_sizes, int n_in,
                              void* d_out, int out_size, void* d_ws, size_t ws_size,
                              hipStream_t stream)
{
    const float* x    = (const float*)d_in[0];
    const float* y    = (const float*)d_in[1];
    const float* b0w1 = (const float*)d_in[2];
    const float* b0s1 = (const float*)d_in[3];
    const float* b0b1 = (const float*)d_in[4];
    const float* b0w2 = (const float*)d_in[5];
    const float* b0s2 = (const float*)d_in[6];
    const float* b0b2 = (const float*)d_in[7];
    const float* b0wd = (const float*)d_in[8];
    const float* b0sd = (const float*)d_in[9];
    const float* b0bd = (const float*)d_in[10];
    const float* bw1  = (const float*)d_in[11];
    const float* bs1  = (const float*)d_in[12];
    const float* bb1  = (const float*)d_in[13];
    const float* bw2  = (const float*)d_in[14];
    const float* bs2  = (const float*)d_in[15];
    const float* bb2  = (const float*)d_in[16];
    const float* offw = (const float*)d_in[17];
    const float* dcw  = (const float*)d_in[18];
    float* out = (float*)d_out;

    // ---- workspace layout (runtime-gated big/fused paths) ----
    const size_t BPK_BIG = 40ull*589824 + 5ull*1474560;   // 30,965,760 B (i8)
    const size_t R0_SER  = 41631744;
    const size_t R0_FUS  = 17694720 + 5ull*16920576;      // 102,297,600
    char* P = (char*)d_ws;
    auto nxt = [&](size_t bytes){ char* r = P; P += (bytes + 255) & ~(size_t)255; return r; };
    double* hbuf = (double*)nxt(14155776);
    u64*  maxbuf = (u64*)nxt(512);
    const size_t NEED_BIG = 14155776 + 512 + 57600 + BPK_BIG + R0_SER + 4096;
    const size_t NEED_FUS = 14155776 + 512 + 57600 + BPK_BIG + (R0_FUS > R0_SER ? R0_FUS : R0_SER) + 8192;
    const bool big   = (ws_size >= NEED_BIG);
    const bool fused = (ws_size >= NEED_FUS) && big;
    int* EbR = (int*)nxt(big ? 57600 : 1536);
    signed char* BpkR = (signed char*)nxt(big ? BPK_BIG : 1474560);
    char* R0 = nxt(fused ? (R0_FUS > R0_SER ? R0_FUS : R0_SER) : R0_SER);
    // trunk phase:
    signed char* actL  = (signed char*)R0;                          //  7,626,752
    signed char* diffL = (signed char*)(R0 + 7626752);              //  3,813,376
    double* diffd = (double*)(R0 + 7626752 + 3813376);              //  1,880,064
    double* res0  = (double*)(R0 + 7626752 + 3813376 + 1880064);    // 14,155,776
    double* obuf  = (double*)(R0 + 7626752 + 3813376 + 1880064 + 14155776); // 14,155,776
    // offsets phase (reuses R0; only hbuf stays live):
    signed char* bigL = (signed char*)R0;                           // 17,694,720
    float* offb = (float*)(R0 + 17694720);                          // 16.9MB (x5 if fused)
    const size_t actLB = 7626752, diffLB = 3813376, bigLB = 17694720;

    auto Bp = [&](int slot)->signed char*{
        if (!big) return BpkR;
        return slot < 40 ? BpkR + (size_t)slot*589824
                         : BpkR + 40ull*589824 + (size_t)(slot-40)*1474560;
    };
    auto Ep = [&](int slot)->int*{ return big ? EbR + slot*320 : EbR; };
    auto prep = [&](int slot){
        if (big) return;
        const float* src; int ocw, ICw, ICpad, OCpad;
        if (slot == 0){ src=b0w1; ocw=128; ICw=17; ICpad=64; OCpad=128; }
        else if (slot == 1){ src=b0w2; ocw=128; ICw=128; ICpad=128; OCpad=128; }
        else if (slot < 40){ int i=(slot-2)>>1;
            src = (((slot-2)&1)? bw2:bw1) + (size_t)i*147456;
            ocw=128; ICw=128; ICpad=128; OCpad=128; }
        else { src = offw + (size_t)(slot-40)*352512; ocw=306; ICw=128; ICpad=128; OCpad=320; }
        hipLaunchKernelGGL(wprep_k, dim3(OCpad), dim3(64), 0, stream,
                           src, BpkR, EbR, ocw, ICw, ICpad, OCpad);
    };

    dim3 b256(256), b128(128);
    hipMemsetAsync(actL, 0, actLB, stream);
    hipMemsetAsync(diffL, 0, diffLB, stream);
    hipMemsetAsync(maxbuf, 0, 512, stream);
    hipMemsetAsync(d_out, 0, (size_t)out_size*sizeof(float), stream);
    if (big)
        hipLaunchKernelGGL(wprep_all, dim3(320,45), dim3(64), 0, stream,
                           b0w1, b0w2, bw1, bw2, offw, BpkR, EbR);

    // diff (+max slot 40), res0
    hipLaunchKernelGGL(diff_kd, dim3(918), b256, 0, stream, x, y, diffd, 235008, maxbuf, 40);
    hipLaunchKernelGGL(conv1x1_d, dim3(432), b256, 0, stream, diffd, b0wd, b0sd, b0bd, res0);
    // blk0 conv1 (limb i8, 17ch pad64): o0 = relu(bn(conv(diff))) -> obuf, max slot 0
    hipLaunchKernelGGL(adecomp17_k, dim3(864), b256, 0, stream, diffd, diffL, maxbuf, 40);
    prep(0);
    hipLaunchKernelGGL((convL<0,1>), dim3(864), b128, 0, stream,
                       diffL, 7448, 76, 1, 1, Bp(0), Ep(0), 128, 4, maxbuf, 40,
                       b0s1, b0b1, (const double*)nullptr, (void*)obuf, maxbuf, 0);
    hipLaunchKernelGGL(adecomp_k, dim3(864), b256, 0, stream, obuf, actL, maxbuf, 0, 7448, 76, 1);
    // blk0 conv2: h0 = relu(bn(conv(o0)) + res0) -> hbuf, max slot 1
    prep(1);
    hipLaunchKernelGGL((convL<1,2>), dim3(864), b128, 0, stream,
                       actL, 7448, 76, 1, 1, Bp(1), Ep(1), 128, 4, maxbuf, 0,
                       b0s2, b0b2, (const double*)res0, (void*)hbuf, maxbuf, 1);
    hipLaunchKernelGGL(adecomp_k, dim3(864), b256, 0, stream, hbuf, actL, maxbuf, 1, 7448, 76, 1);

    for (int i = 0; i < 19; i++){
        const int sIn = 2*i + 1, sO = 2*i + 2, sH = 2*i + 3;
        prep(2+2*i);
        hipLaunchKernelGGL((convL<0,2>), dim3(864), b128, 0, stream,
                           actL, 7448, 76, 1, 1, Bp(2+2*i), Ep(2+2*i), 128, 4, maxbuf, sIn,
                           bs1 + i*128, bb1 + i*128, (const double*)nullptr,
                           (void*)obuf, maxbuf, sO);
        hipLaunchKernelGGL(adecomp_k, dim3(864), b256, 0, stream, obuf, actL, maxbuf, sO, 7448, 76, 1);
        prep(3+2*i);
        hipLaunchKernelGGL((convL<1,2>), dim3(864), b128, 0, stream,
                           actL, 7448, 76, 1, 1, Bp(3+2*i), Ep(3+2*i), 128, 4, maxbuf, sO,
                           bs2 + i*128, bb2 + i*128, (const double*)hbuf,
                           (void*)hbuf, maxbuf, sH);
        if (i < 18)
            hipLaunchKernelGGL(adecomp_k, dim3(864), b256, 0, stream, hbuf, actL, maxbuf, sH, 7448, 76, 1);
    }

    // offsets + deform (feat = hbuf, max slot 39)
    hipMemsetAsync(bigL, 0, bigLB, stream);
    hipLaunchKernelGGL(adecomp_k, dim3(864), b256, 0, stream, hbuf, bigL, maxbuf, 39, 17280, 120, 24);
    if (fused){
        hipLaunchKernelGGL(convLo, dim3(10800), b256, 0, stream,
                           bigL, 17280, 120, 24, Bp(40), Ep(40), maxbuf, 39, offb);
        hipLaunchKernelGGL(deform_all, dim3(4320), b256, 0, stream, x, offb, dcw, out);
    } else {
        const int dils[5] = {3,6,12,18,24};
        for (int d = 0; d < 5; d++){
            prep(40+d);
            hipLaunchKernelGGL((convL<2,2>), dim3(1080), b128, 0, stream,
                               bigL, 17280, 120, 24, dils[d], Bp(40+d), Ep(40+d), 306, 10, maxbuf, 39,
                               (const float*)nullptr, (const float*)nullptr,
                               (const double*)nullptr, (void*)offb, (u64*)nullptr, 0);
            hipLaunchKernelGGL(deform_kd, dim3(864), b256, 0, stream,
                               x, offb, dcw + (size_t)d*2601, out, dils[d]);
        }
    }
}

// Round 22
// 2983.414 us; speedup vs baseline: 1.0574x; 1.0574x over previous
//
#include <hip/hip_runtime.h>
#include <hip/hip_bf16.h>

#define NPX 6912   // 96*72
typedef unsigned long long u64;
typedef int i32x4 __attribute__((ext_vector_type(4)));

__device__ __forceinline__ int ea_from_bits(u64 bits){
    double m = __longlong_as_double((long long)bits);
    if (!(m > 0.0)) return 0;
    return ilogb(m) + 1;
}
// balanced radix-256 digits of round(a*2^sh): q = ((d0*256+d1)*256+d2)*256+d3 exactly
__device__ __forceinline__ void digits4(double a, int sh, int& d0, int& d1, int& d2, int& d3){
    long long q = __double2ll_rn(ldexp(a, sh));
    d3 = (int)(((q + 128) & 255) - 128); q = (q - d3) >> 8;
    d2 = (int)(((q + 128) & 255) - 128); q = (q - d2) >> 8;
    d1 = (int)(((q + 128) & 255) - 128);
    d0 = (int)((q - d1) >> 8);
}
// bijective XCD swizzle (requires nwg % 8 == 0)
__device__ __forceinline__ int xcd_swz(int bid, int nwg){
    return (bid & 7) * (nwg >> 3) + (bid >> 3);
}

// ---------------- diff = y - x (f64) + absmax -> maxbuf[slot] ----------------
__global__ __launch_bounds__(256) void diff_kd(const float* __restrict__ x,
    const float* __restrict__ y, double* __restrict__ d, int n,
    u64* maxbuf, int slot){
    int i = blockIdx.x*256 + threadIdx.x;
    double m = 0.0;
    if (i < n){ double v = (double)y[i] - (double)x[i]; d[i] = v; m = fabs(v); }
    #pragma unroll
    for (int o=32;o;o>>=1) m = fmax(m, __shfl_down(m,o));
    __shared__ double W[4];
    if ((threadIdx.x&63)==0) W[threadIdx.x>>6]=m;
    __syncthreads();
    if (threadIdx.x==0){
        m = fmax(fmax(W[0],W[1]),fmax(W[2],W[3]));
        atomicMax(maxbuf+slot,(u64)__double_as_longlong(m));
    }
}

// ---------------- 1x1 conv 17->128 + bn, fp64 ----------------
__global__ __launch_bounds__(256) void conv1x1_d(const double* __restrict__ in,
    const float* __restrict__ wgt, const float* __restrict__ scale,
    const float* __restrict__ shift, double* __restrict__ out){
    __shared__ float Ws[17*128];
    const int t = threadIdx.x;
    for (int e=t; e<17*128; e+=256){
        int ic = e >> 7, oc = e & 127;
        Ws[e] = wgt[oc*17 + ic];
    }
    __syncthreads();
    const int pxl = t & 31, ocg = t >> 5;
    const int p = blockIdx.x*32 + pxl;
    const int b = p / NPX, pi = p - b*NPX;
    double acc[16];
    #pragma unroll
    for (int j=0;j<16;j++) acc[j]=0.0;
    const double* inb = in + (size_t)b*17*NPX + pi;
    #pragma unroll
    for (int ic=0;ic<17;ic++){
        const double a = inb[(size_t)ic*NPX];
        #pragma unroll
        for (int j=0;j<16;j++) acc[j] = fma(a, (double)Ws[(ic<<7)+(ocg<<4)+j], acc[j]);
    }
    #pragma unroll
    for (int j=0;j<16;j++){
        const int oc = (ocg<<4)+j;
        out[((size_t)b*128+oc)*NPX + pi] = fma(acc[j], (double)scale[oc], (double)shift[oc]);
    }
}

// ---------------- activation decompose: f64 [2][128][NPX] -> i8 [4][2][PS][128] ----
// grid 1728 (2b x 864 eight-px groups)  [R19 config — best measured]
__global__ __launch_bounds__(256) void adecomp_k(const double* __restrict__ src,
    signed char* __restrict__ dst, const u64* __restrict__ maxbuf, int slot,
    int PS, int PW, int PB)
{
    __shared__ signed char L[4][8][128];   // 4 KB
    const int t = threadIdx.x;
    const int b = blockIdx.x / 864, px0 = (blockIdx.x % 864) * 8;
    const int sh = 30 - ea_from_bits(maxbuf[slot]);
    const int tp = t & 7, tc = t >> 3;     // 8 px x 32 c-lanes
    #pragma unroll
    for (int i=0;i<4;i++){
        const int c = tc + i*32;
        double a = src[((size_t)b*128 + c)*NPX + px0 + tp];
        int d0,d1,d2,d3; digits4(a, sh, d0,d1,d2,d3);
        L[0][tp][c] = (signed char)d0;
        L[1][tp][c] = (signed char)d1;
        L[2][tp][c] = (signed char)d2;
        L[3][tp][c] = (signed char)d3;
    }
    __syncthreads();
    const int l = t >> 6, px = (t >> 3) & 7, chunk = t & 7;   // 256 x 16B chunks
    const int pix = px0 + px, yy = pix/72, xx = pix - yy*72;
    const size_t po = ((size_t)(l*2+b)*PS + (size_t)(yy+PB)*PW + (xx+PB))*128 + chunk*16;
    *(uint4*)(dst+po) = *(const uint4*)(&L[l][px][chunk*16]);
}

// ---------------- diff decompose: f64 [2][17][NPX] -> i8 [4][2][7448][64] ----
__global__ __launch_bounds__(256) void adecomp17_k(const double* __restrict__ src,
    signed char* __restrict__ dst, const u64* __restrict__ maxbuf, int slot)
{
    __shared__ signed char L[4][16][64];    // 4 KB
    const int t = threadIdx.x;
    const int b = blockIdx.x / 432, px0 = (blockIdx.x % 432) * 16;
    const int sh = 30 - ea_from_bits(maxbuf[slot]);
    uint4 z = {0,0,0,0};
    *(uint4*)(((signed char*)L) + t*16) = z;   // zero all 4096 B
    __syncthreads();
    const int tp = t & 15, tc = t >> 4;
    #pragma unroll
    for (int i=0;i<2;i++){
        const int c = tc + i*16;
        if (c < 17){
            double a = src[((size_t)b*17 + c)*NPX + px0 + tp];
            int d0,d1,d2,d3; digits4(a, sh, d0,d1,d2,d3);
            L[0][tp][c] = (signed char)d0;
            L[1][tp][c] = (signed char)d1;
            L[2][tp][c] = (signed char)d2;
            L[3][tp][c] = (signed char)d3;
        }
    }
    __syncthreads();
    const int l = t >> 6, wpx = (t >> 2) & 15, chunk = t & 3;
    const int pix = px0 + wpx, yy = pix/72, xx = pix - yy*72;
    const size_t po = ((size_t)(l*2+b)*7448 + (size_t)(yy+1)*76 + (xx+1))*64 + chunk*16;
    *(uint4*)(dst+po) = *(const uint4*)(&L[l][wpx][chunk*16]);
}

// ------- weight prepack: fp32 [ocw][ICw][9] -> i8 per-tap 4*32*ICpad units, swizzled ----
// unit layout: [l][o32][xk][16]; ICpad=128: xk = k16 ^ (o32&7); ICpad=64: xk = k16 ^ ((o32>>1)&3)
__device__ __forceinline__ void wprep_body(const float* src,
    signed char* Bpk, int* Eb, int oc, int t,
    int ocw, int ICw, int ICpad, int OCpad)
{
    const int NW = ICw*9;
    float m = 0.f;
    if (oc < ocw)
        for (int e=t;e<NW;e+=64) m = fmaxf(m, fabsf(src[(size_t)oc*NW+e]));
    #pragma unroll
    for (int o=32;o;o>>=1) m = fmaxf(m, __shfl_down(m,o));
    m = __shfl(m, 0);
    const int Ebv = (m>0.f)?(ilogbf(m)+1):0;
    if (t==0) Eb[oc]=Ebv;
    const int sh = 30 - Ebv;
    const int nc16 = ICpad >> 4;
    const int PERSTEP = 4*32*ICpad;
    const size_t perOt = (size_t)9*PERSTEP;
    const int ot = oc >> 5, o32 = oc & 31;
    const int nchunks = nc16*9;
    for (int mci=t; mci<nchunks; mci+=64){
        const int ic16 = mci % nc16, tap = mci / nc16;
        const int xk = (ICpad==128) ? (ic16 ^ (o32 & 7)) : (ic16 ^ ((o32>>1) & 3));
        __align__(16) signed char dig[4][16];
        #pragma unroll
        for (int j=0;j<16;j++){
            const int ic = ic16*16+j;
            float w = (oc<ocw && ic<ICw) ? src[((size_t)oc*ICw+ic)*9+tap] : 0.f;
            int d0,d1,d2,d3; digits4((double)w, sh, d0,d1,d2,d3);
            dig[0][j]=(signed char)d0;
            dig[1][j]=(signed char)d1;
            dig[2][j]=(signed char)d2;
            dig[3][j]=(signed char)d3;
        }
        const size_t base = (size_t)ot*perOt + (size_t)tap*PERSTEP
                          + (size_t)o32*ICpad + (xk<<4);
        #pragma unroll
        for (int l=0;l<4;l++)
            *(uint4*)(Bpk + base + (size_t)l*32*ICpad) = *(const uint4*)(&dig[l][0]);
    }
}

__global__ __launch_bounds__(64) void wprep_k(const float* __restrict__ wgt,
    signed char* __restrict__ Bpk, int* __restrict__ Eb,
    int ocw, int ICw, int ICpad, int OCpad)
{
    wprep_body(wgt, Bpk, Eb, blockIdx.x, threadIdx.x, ocw, ICw, ICpad, OCpad);
}

// all 45 layers in one launch. slots: 0=b0w1(IC17,pad64) 1=b0w2 2+2i=bw1[i] 3+2i=bw2[i] 40+d=offw[d]
__global__ __launch_bounds__(64) void wprep_all(
    const float* __restrict__ b0w1, const float* __restrict__ b0w2,
    const float* __restrict__ bw1, const float* __restrict__ bw2,
    const float* __restrict__ offw,
    signed char* __restrict__ BpkAll, int* __restrict__ EbAll)
{
    const int slot = blockIdx.y;
    const float* src; int ocw, ICw, ICpad, OCpad;
    signed char* Bpk;
    if (slot < 40){
        Bpk = BpkAll + (size_t)slot * 589824;
        ocw = 128; OCpad = 128;
        if (slot == 0){ src=b0w1; ICw=17; ICpad=64; }
        else if (slot == 1){ src=b0w2; ICw=128; ICpad=128; }
        else { int i=(slot-2)>>1; src = (((slot-2)&1)? bw2:bw1) + (size_t)i*147456; ICw=128; ICpad=128; }
    } else {
        Bpk = BpkAll + 40ull*589824 + (size_t)(slot-40)*1474560;
        src = offw + (size_t)(slot-40)*352512; ocw=306; ICw=128; ICpad=128; OCpad=320;
    }
    if ((int)blockIdx.x >= OCpad) return;
    wprep_body(src, Bpk, EbAll + slot*320, blockIdx.x, threadIdx.x, ocw, ICw, ICpad, OCpad);
}

// ---- exact limb-MFMA(i8) trunk conv: 2-wave blocks, 32px x 32oc per wave (R19 cfg) ----
#define MFI(A,B,C) __builtin_amdgcn_mfma_i32_16x16x64_i8(A,B,C,0,0,0)

template<int MODE, int NCC>
__global__ __launch_bounds__(128, 2) void convL(
    const signed char* __restrict__ inL, int PS, int PW, int PB, int dil,
    const signed char* __restrict__ Bpk, const int* __restrict__ Eb,
    int OCw, int OCT,
    const u64* __restrict__ maxbuf, int easlot,
    const float* __restrict__ scale, const float* __restrict__ shift,
    const double* res, void* outp, u64* maxout, int moslot)
{
    constexpr int CC = NCC*64;
    constexpr int NSTEP = 9;
    constexpr int PERSTEP = 4*32*CC;          // 8KB (NCC=1) / 16KB (NCC=2)
    constexpr int LSTR = 32*CC;
    constexpr int NCHUNK = PERSTEP/2048;      // per-thread 16B chunks (128 thr)
    __shared__ signed char Bs[2][PERSTEP];    // 16/32 KB
    const int t = threadIdx.x;
    const int w = t >> 6, lane = t & 63;
    const int ocl = lane & 15, rq = lane >> 4;
    const int lb = xcd_swz(blockIdx.x, gridDim.x);
    const int oct = lb % OCT, pxt = lb / OCT;
    const int b = pxt / 108, px0 = (pxt - b*108) * 64 + w*32;
    const int oc0 = oct * 32;

    long long aBase[2];
    #pragma unroll
    for (int mt=0; mt<2; mt++){
        const int px = px0 + mt*16 + ocl;
        const int sy = px/72, sx = px - sy*72;
        aBase[mt] = ((long long)b*PS + (long long)(sy+PB)*PW + (sx+PB))*CC + rq*16;
    }
    const long long pStr = (long long)2*PS*CC;
    const signed char* Bsl = Bpk + (size_t)oct * ((size_t)NSTEP*PERSTEP);

    i32x4 c0[2][2], c1[2][2], c2[2][2], c3[2][2];   // [mt][nt]
    #pragma unroll
    for (int i=0;i<2;i++)
      #pragma unroll
      for (int j=0;j<2;j++){
        c0[i][j]=(i32x4)(0); c1[i][j]=(i32x4)(0);
        c2[i][j]=(i32x4)(0); c3[i][j]=(i32x4)(0);
      }

    const int Ea = ea_from_bits(maxbuf[easlot]);

    auto STAGE = [&](int s, int buf){
        const signed char* src = Bsl + (size_t)s*PERSTEP + w*1024 + (lane<<4);
        #pragma unroll
        for (int j=0;j<NCHUNK;j++)
            __builtin_amdgcn_global_load_lds((const unsigned int*)(src + j*2048),
                                             (unsigned int*)(&Bs[buf][j*2048 + w*1024]), 16, 0, 0);
    };

    STAGE(0, 0);
    __builtin_amdgcn_sched_barrier(0);

    for (int s=0; s<NSTEP; s++){
        if (s == 0)           asm volatile("s_waitcnt vmcnt(0)  lgkmcnt(0)" ::: "memory");
        else if (NCC==2)      asm volatile("s_waitcnt vmcnt(16) lgkmcnt(0)" ::: "memory");
        else                  asm volatile("s_waitcnt vmcnt(8)  lgkmcnt(0)" ::: "memory");
        __builtin_amdgcn_s_barrier();
        __builtin_amdgcn_sched_barrier(0);

        if (s+1 < NSTEP) STAGE(s+1, (s+1)%2);

        const int ty = s/3, tx = s - ty*3;
        const long long dofs = ((long long)(ty-1)*PW + (tx-1)) * dil * CC;
        const signed char* bsb = &Bs[s%2][0];

        i32x4 af[NCC][2][4];    // [icc][mt][l]
        #pragma unroll
        for (int icc=0; icc<NCC; icc++)
          #pragma unroll
          for (int mt=0; mt<2; mt++)
            #pragma unroll
            for (int l=0;l<4;l++)
                af[icc][mt][l] = *(const i32x4*)(inL + (aBase[mt] + dofs + icc*64 + (long long)l*pStr));

        i32x4 bfr[NCC][2][4];   // [icc][nt][l]
        #pragma unroll
        for (int icc=0; icc<NCC; icc++)
          #pragma unroll
          for (int nt=0; nt<2; nt++){
            const int o32 = nt*16 + ocl;
            const int xk = (NCC==2) ? ((icc*4+rq) ^ (o32 & 7)) : (rq ^ ((o32>>1) & 3));
            const int off = o32*CC + (xk<<4);
            #pragma unroll
            for (int l=0;l<4;l++)
                bfr[icc][nt][l] = *(const i32x4*)(bsb + l*LSTR + off);
          }

        __builtin_amdgcn_s_setprio(1);
        #pragma unroll
        for (int icc=0; icc<NCC; icc++)
          #pragma unroll
          for (int nt=0; nt<2; nt++)
            #pragma unroll
            for (int mt=0; mt<2; mt++){
              c0[mt][nt]=MFI(af[icc][mt][0],bfr[icc][nt][0],c0[mt][nt]);
              c1[mt][nt]=MFI(af[icc][mt][0],bfr[icc][nt][1],c1[mt][nt]);
              c1[mt][nt]=MFI(af[icc][mt][1],bfr[icc][nt][0],c1[mt][nt]);
              c2[mt][nt]=MFI(af[icc][mt][0],bfr[icc][nt][2],c2[mt][nt]);
              c2[mt][nt]=MFI(af[icc][mt][1],bfr[icc][nt][1],c2[mt][nt]);
              c2[mt][nt]=MFI(af[icc][mt][2],bfr[icc][nt][0],c2[mt][nt]);
              c3[mt][nt]=MFI(af[icc][mt][0],bfr[icc][nt][3],c3[mt][nt]);
              c3[mt][nt]=MFI(af[icc][mt][1],bfr[icc][nt][2],c3[mt][nt]);
              c3[mt][nt]=MFI(af[icc][mt][2],bfr[icc][nt][1],c3[mt][nt]);
              c3[mt][nt]=MFI(af[icc][mt][3],bfr[icc][nt][0],c3[mt][nt]);
            }
        __builtin_amdgcn_s_setprio(0);
    }

    if (MODE != 2){
        double mx = 0.0;
        #pragma unroll
        for (int nt=0;nt<2;nt++){
            const int oc = oc0 + nt*16 + ocl;
            const int ex = Ea + Eb[oc] - 36;
            const double sc = (double)scale[oc], sf = (double)shift[oc];
            #pragma unroll
            for (int mt=0;mt<2;mt++){
                const size_t ob = ((size_t)(b*128+oc))*NPX + px0 + mt*16 + rq*4;
                double4 rv;
                if (MODE==1) rv = *(const double4*)(res+ob);
                double vv[4];
                #pragma unroll
                for (int v=0;v<4;v++){
                    const long long comb = ((long long)c0[mt][nt][v]<<24) + ((long long)c1[mt][nt][v]<<16)
                                         + ((long long)c2[mt][nt][v]<<8)  +  (long long)c3[mt][nt][v];
                    double dv = fma(ldexp((double)comb, ex), sc, sf);
                    if (MODE==1) dv += (&rv.x)[v];
                    dv = dv>0.0 ? dv : 0.0;
                    vv[v]=dv; mx = fmax(mx,dv);
                }
                double4 st = {vv[0],vv[1],vv[2],vv[3]};
                *(double4*)((double*)outp+ob) = st;
            }
        }
        #pragma unroll
        for (int o=32;o;o>>=1) mx = fmax(mx,__shfl_down(mx,o));
        if (lane==0) atomicMax(maxout+moslot,(u64)__double_as_longlong(mx));
    } else {
        #pragma unroll
        for (int nt=0;nt<2;nt++){
            const int oc = oc0 + nt*16 + ocl;
            if (oc < OCw){
                const int ex = Ea + Eb[oc] - 36;
                #pragma unroll
                for (int mt=0;mt<2;mt++){
                    const size_t ob = ((size_t)b*OCw+oc)*NPX + px0 + mt*16 + rq*4;
                    float4 st;
                    #pragma unroll
                    for (int v=0;v<4;v++){
                        const long long comb = ((long long)c0[mt][nt][v]<<24) + ((long long)c1[mt][nt][v]<<16)
                                             + ((long long)c2[mt][nt][v]<<8)  +  (long long)c3[mt][nt][v];
                        (&st.x)[v] = (float)ldexp((double)comb, ex);
                    }
                    *(float4*)((float*)outp+ob) = st;
                }
            }
        }
    }
}

// ---- FUSED offset conv: 16px x 32oc per wave, all 5 dilations (R17/R18 cfg, verbatim) ----
__global__ __launch_bounds__(256, 2) void convLo(
    const signed char* __restrict__ inL, int PS, int PW, int PB,
    const signed char* __restrict__ BpkAll, const int* __restrict__ EbAll,
    const u64* __restrict__ maxbuf, int easlot, float* __restrict__ outAll)
{
    constexpr int CC = 128;
    constexpr int NSTEP = 9;
    constexpr int PERSTEP = 4*32*CC;          // 16KB
    constexpr int LSTR = 32*CC;
    __shared__ signed char Bs[2][PERSTEP];    // 32 KB
    const int t = threadIdx.x;
    const int w = t >> 6, lane = t & 63;
    const int ocl = lane & 15, rq = lane >> 4;
    const int lb = xcd_swz(blockIdx.x, gridDim.x);
    const int d = lb / 2160, r = lb - d*2160;
    const int dil = d ? 6*d : 3;
    const int oct = r % 10, pxt = r / 10;
    const int b = pxt / 108, px0 = (pxt - b*108) * 64 + w*16;
    const int oc0 = oct * 32;
    const int* Eb = EbAll + d*320;
    float* outp = outAll + (size_t)d*4230144;

    const int px = px0 + ocl;
    const int sy = px/72, sx = px - sy*72;
    const long long aBase = ((long long)b*PS + (long long)(sy+PB)*PW + (sx+PB))*CC + rq*16;
    const long long pStr = (long long)2*PS*CC;
    const signed char* Bsl = BpkAll + (size_t)d*1474560 + (size_t)oct * ((size_t)NSTEP*PERSTEP);

    i32x4 c0[2], c1[2], c2[2], c3[2];
    #pragma unroll
    for (int j=0;j<2;j++){
        c0[j]=(i32x4)(0); c1[j]=(i32x4)(0);
        c2[j]=(i32x4)(0); c3[j]=(i32x4)(0);
    }

    const int Ea = ea_from_bits(maxbuf[easlot]);

    auto STAGE = [&](int s, int buf){
        const signed char* src = Bsl + (size_t)s*PERSTEP + w*1024 + (lane<<4);
        #pragma unroll
        for (int j=0;j<PERSTEP/4096;j++)
            __builtin_amdgcn_global_load_lds((const unsigned int*)(src + j*4096),
                                             (unsigned int*)(&Bs[buf][j*4096 + w*1024]), 16, 0, 0);
    };

    STAGE(0, 0);
    __builtin_amdgcn_sched_barrier(0);

    for (int s=0; s<NSTEP; s++){
        if (s == 0) asm volatile("s_waitcnt vmcnt(0) lgkmcnt(0)" ::: "memory");
        else        asm volatile("s_waitcnt vmcnt(8) lgkmcnt(0)" ::: "memory");
        __builtin_amdgcn_s_barrier();
        __builtin_amdgcn_sched_barrier(0);

        if (s+1 < NSTEP) STAGE(s+1, (s+1)%2);

        const int ty = s/3, tx = s - ty*3;
        const long long dofs = ((long long)(ty-1)*PW + (tx-1)) * dil * CC;
        const signed char* bsb = &Bs[s%2][0];

        i32x4 af[2][4];    // [icc][l]
        #pragma unroll
        for (int icc=0; icc<2; icc++)
          #pragma unroll
          for (int l=0;l<4;l++)
            af[icc][l] = *(const i32x4*)(inL + (aBase + dofs + icc*64 + (long long)l*pStr));

        i32x4 bfr[2][2][4];   // [icc][nt][l]
        #pragma unroll
        for (int icc=0; icc<2; icc++)
          #pragma unroll
          for (int nt=0; nt<2; nt++){
            const int o32 = nt*16 + ocl;
            const int xk = (icc*4+rq) ^ (o32 & 7);
            const int off = o32*CC + (xk<<4);
            #pragma unroll
            for (int l=0;l<4;l++)
                bfr[icc][nt][l] = *(const i32x4*)(bsb + l*LSTR + off);
          }

        __builtin_amdgcn_s_setprio(1);
        #pragma unroll
        for (int icc=0; icc<2; icc++)
          #pragma unroll
          for (int nt=0; nt<2; nt++){
            c0[nt]=MFI(af[icc][0],bfr[icc][nt][0],c0[nt]);
            c1[nt]=MFI(af[icc][0],bfr[icc][nt][1],c1[nt]);
            c1[nt]=MFI(af[icc][1],bfr[icc][nt][0],c1[nt]);
            c2[nt]=MFI(af[icc][0],bfr[icc][nt][2],c2[nt]);
            c2[nt]=MFI(af[icc][1],bfr[icc][nt][1],c2[nt]);
            c2[nt]=MFI(af[icc][2],bfr[icc][nt][0],c2[nt]);
            c3[nt]=MFI(af[icc][0],bfr[icc][nt][3],c3[nt]);
            c3[nt]=MFI(af[icc][1],bfr[icc][nt][2],c3[nt]);
            c3[nt]=MFI(af[icc][2],bfr[icc][nt][1],c3[nt]);
            c3[nt]=MFI(af[icc][3],bfr[icc][nt][0],c3[nt]);
          }
        __builtin_amdgcn_s_setprio(0);
    }

    #pragma unroll
    for (int nt=0;nt<2;nt++){
        const int oc = oc0 + nt*16 + ocl;
        if (oc < 306){
            const int ex = Ea + Eb[oc] - 36;
            const size_t ob = ((size_t)b*306+oc)*NPX + px0 + rq*4;
            float4 st;
            #pragma unroll
            for (int v=0;v<4;v++){
                const long long comb = ((long long)c0[nt][v]<<24) + ((long long)c1[nt][v]<<16)
                                     + ((long long)c2[nt][v]<<8)  +  (long long)c3[nt][v];
                (&st.x)[v] = (float)ldexp((double)comb, ex);
            }
            *(float4*)(outp+ob) = st;
        }
    }
}

// ------ deformable conv body, fp64, 16px x 16 c-groups + LDS reduce, 0.2x into out ----
__device__ __forceinline__ void deform_body(
    const float* xin, const float* off, const float* dcw, float* out, int dil,
    int blk, int t)
{
    __shared__ float Wsm[17*153];
    __shared__ double R[16][16][17];      // 34.8 KB
    for (int e=t;e<17*153;e+=256) Wsm[e] = dcw[e];
    __syncthreads();
    const int pxl = t & 15, cg = t >> 4;
    const int p = blk*16 + pxl;           // 864*16 = 13824
    const int b = p / NPX, pi = p - b*NPX;
    const int yy = pi/72, xx = pi - yy*72;
    const float* img = xin + (size_t)b*17*NPX;
    const float* ob  = off + (size_t)b*306*NPX + pi;
    const int cbeg = (cg==0) ? 0 : (cg+1);
    const int cnt  = (cg==0) ? 2 : 1;
    double acc[17];
    #pragma unroll
    for (int o=0;o<17;o++) acc[o]=0.0;
    for (int ci=0; ci<cnt; ci++){
        const int c = cbeg + ci;
        const float* im = img + c*NPX;
        #pragma unroll
        for (int k=0;k<9;k++){
            const double dy = (double)ob[((c*9+k)*2+0)*NPX];
            const double dx = (double)ob[((c*9+k)*2+1)*NPX];
            const double py  = (double)yy + dy + (double)((k/3-1)*dil);
            const double pxd = (double)xx + dx + (double)((k%3-1)*dil);
            const double y0f = floor(py), x0f = floor(pxd);
            const double wy = py - y0f, wx = pxd - x0f;
            const int y0 = (int)fmax(fmin(y0f, 97.0), -2.0);
            const int x0 = (int)fmax(fmin(x0f, 73.0), -2.0);
            const bool yv0 = (y0   >= 0) && (y0   < 96);
            const bool yv1 = (y0+1 >= 0) && (y0+1 < 96);
            const bool xv0 = (x0   >= 0) && (x0   < 72);
            const bool xv1 = (x0+1 >= 0) && (x0+1 < 72);
            const int yc0 = min(max(y0  ,0),95), yc1 = min(max(y0+1,0),95);
            const int xc0 = min(max(x0  ,0),71), xc1 = min(max(x0+1,0),71);
            const double v00 = (yv0&&xv0) ? (double)im[yc0*72+xc0] : 0.0;
            const double v01 = (yv0&&xv1) ? (double)im[yc0*72+xc1] : 0.0;
            const double v10 = (yv1&&xv0) ? (double)im[yc1*72+xc0] : 0.0;
            const double v11 = (yv1&&xv1) ? (double)im[yc1*72+xc1] : 0.0;
            const double s = v00*(1.0-wy)*(1.0-wx) + v01*(1.0-wy)*wx
                           + v10*wy*(1.0-wx)       + v11*wy*wx;
            const int ck = c*9+k;
            #pragma unroll
            for (int o=0;o<17;o++)
                acc[o] = fma((double)Wsm[o*153+ck], s, acc[o]);
        }
    }
    #pragma unroll
    for (int o=0;o<17;o++) R[cg][pxl][o] = acc[o];
    __syncthreads();
    const int og = cg;
    const int obeg = (og==0) ? 0 : (og+1);
    const int ocnt = (og==0) ? 2 : 1;
    for (int oi=0; oi<ocnt; oi++){
        const int o = obeg + oi;
        double s = 0.0;
        #pragma unroll
        for (int g=0; g<16; g++) s += R[g][pxl][o];
        atomicAdd(out + ((size_t)b*17+o)*NPX + pi, (float)(0.2*s));
    }
}

__global__ __launch_bounds__(256) void deform_kd(
    const float* __restrict__ xin, const float* __restrict__ off,
    const float* __restrict__ dcw, float* out, int dil)
{
    deform_body(xin, off, dcw, out, dil, blockIdx.x, threadIdx.x);
}

// fused: grid 4320 = 5 dil x 864
__global__ __launch_bounds__(256) void deform_all(
    const float* __restrict__ xin, const float* __restrict__ offAll,
    const float* __restrict__ dcwAll, float* out)
{
    const int d = blockIdx.x / 864, blk = blockIdx.x - d*864;
    const int dil = d ? 6*d : 3;
    deform_body(xin, offAll + (size_t)d*4230144, dcwAll + d*2601, out, dil,
                blk, threadIdx.x);
}

extern "C" void kernel_launch(void* const* d_in, const int* in_sizes, int n_in,
                              void* d_out, int out_size, void* d_ws, size_t ws_size,
                              hipStream_t stream)
{
    const float* x    = (const float*)d_in[0];
    const float* y    = (const float*)d_in[1];
    const float* b0w1 = (const float*)d_in[2];
    const float* b0s1 = (const float*)d_in[3];
    const float* b0b1 = (const float*)d_in[4];
    const float* b0w2 = (const float*)d_in[5];
    const float* b0s2 = (const float*)d_in[6];
    const float* b0b2 = (const float*)d_in[7];
    const float* b0wd = (const float*)d_in[8];
    const float* b0sd = (const float*)d_in[9];
    const float* b0bd = (const float*)d_in[10];
    const float* bw1  = (const float*)d_in[11];
    const float* bs1  = (const float*)d_in[12];
    const float* bb1  = (const float*)d_in[13];
    const float* bw2  = (const float*)d_in[14];
    const float* bs2  = (const float*)d_in[15];
    const float* bb2  = (const float*)d_in[16];
    const float* offw = (const float*)d_in[17];
    const float* dcw  = (const float*)d_in[18];
    float* out = (float*)d_out;

    // ---- workspace layout (runtime-gated big/fused paths) ----
    const size_t BPK_BIG = 40ull*589824 + 5ull*1474560;   // 30,965,760 B (i8)
    const size_t R0_SER  = 41631744;
    const size_t R0_FUS  = 17694720 + 5ull*16920576;      // 102,297,600
    char* P = (char*)d_ws;
    auto nxt = [&](size_t bytes){ char* r = P; P += (bytes + 255) & ~(size_t)255; return r; };
    double* hbuf = (double*)nxt(14155776);
    u64*  maxbuf = (u64*)nxt(512);
    const size_t NEED_BIG = 14155776 + 512 + 57600 + BPK_BIG + R0_SER + 4096;
    const size_t NEED_FUS = 14155776 + 512 + 57600 + BPK_BIG + (R0_FUS > R0_SER ? R0_FUS : R0_SER) + 8192;
    const bool big   = (ws_size >= NEED_BIG);
    const bool fused = (ws_size >= NEED_FUS) && big;
    int* EbR = (int*)nxt(big ? 57600 : 1536);
    signed char* BpkR = (signed char*)nxt(big ? BPK_BIG : 1474560);
    char* R0 = nxt(fused ? (R0_FUS > R0_SER ? R0_FUS : R0_SER) : R0_SER);
    // trunk phase:
    signed char* actL  = (signed char*)R0;                          //  7,626,752
    signed char* diffL = (signed char*)(R0 + 7626752);              //  3,813,376
    double* diffd = (double*)(R0 + 7626752 + 3813376);              //  1,880,064
    double* res0  = (double*)(R0 + 7626752 + 3813376 + 1880064);    // 14,155,776
    double* obuf  = (double*)(R0 + 7626752 + 3813376 + 1880064 + 14155776); // 14,155,776
    // offsets phase (reuses R0; only hbuf stays live):
    signed char* bigL = (signed char*)R0;                           // 17,694,720
    float* offb = (float*)(R0 + 17694720);                          // 16.9MB (x5 if fused)
    const size_t actLB = 7626752, diffLB = 3813376, bigLB = 17694720;

    auto Bp = [&](int slot)->signed char*{
        if (!big) return BpkR;
        return slot < 40 ? BpkR + (size_t)slot*589824
                         : BpkR + 40ull*589824 + (size_t)(slot-40)*1474560;
    };
    auto Ep = [&](int slot)->int*{ return big ? EbR + slot*320 : EbR; };
    auto prep = [&](int slot){
        if (big) return;
        const float* src; int ocw, ICw, ICpad, OCpad;
        if (slot == 0){ src=b0w1; ocw=128; ICw=17; ICpad=64; OCpad=128; }
        else if (slot == 1){ src=b0w2; ocw=128; ICw=128; ICpad=128; OCpad=128; }
        else if (slot < 40){ int i=(slot-2)>>1;
            src = (((slot-2)&1)? bw2:bw1) + (size_t)i*147456;
            ocw=128; ICw=128; ICpad=128; OCpad=128; }
        else { src = offw + (size_t)(slot-40)*352512; ocw=306; ICw=128; ICpad=128; OCpad=320; }
        hipLaunchKernelGGL(wprep_k, dim3(OCpad), dim3(64), 0, stream,
                           src, BpkR, EbR, ocw, ICw, ICpad, OCpad);
    };

    dim3 b256(256), b128(128);
    hipMemsetAsync(actL, 0, actLB, stream);
    hipMemsetAsync(diffL, 0, diffLB, stream);
    hipMemsetAsync(maxbuf, 0, 512, stream);
    hipMemsetAsync(d_out, 0, (size_t)out_size*sizeof(float), stream);
    if (big)
        hipLaunchKernelGGL(wprep_all, dim3(320,45), dim3(64), 0, stream,
                           b0w1, b0w2, bw1, bw2, offw, BpkR, EbR);

    // diff (+max slot 40), res0
    hipLaunchKernelGGL(diff_kd, dim3(918), b256, 0, stream, x, y, diffd, 235008, maxbuf, 40);
    hipLaunchKernelGGL(conv1x1_d, dim3(432), b256, 0, stream, diffd, b0wd, b0sd, b0bd, res0);
    // blk0 conv1 (limb i8, 17ch pad64): o0 = relu(bn(conv(diff))) -> obuf, max slot 0
    hipLaunchKernelGGL(adecomp17_k, dim3(864), b256, 0, stream, diffd, diffL, maxbuf, 40);
    prep(0);
    hipLaunchKernelGGL((convL<0,1>), dim3(864), b128, 0, stream,
                       diffL, 7448, 76, 1, 1, Bp(0), Ep(0), 128, 4, maxbuf, 40,
                       b0s1, b0b1, (const double*)nullptr, (void*)obuf, maxbuf, 0);
    hipLaunchKernelGGL(adecomp_k, dim3(1728), b256, 0, stream, obuf, actL, maxbuf, 0, 7448, 76, 1);
    // blk0 conv2: h0 = relu(bn(conv(o0)) + res0) -> hbuf, max slot 1
    prep(1);
    hipLaunchKernelGGL((convL<1,2>), dim3(864), b128, 0, stream,
                       actL, 7448, 76, 1, 1, Bp(1), Ep(1), 128, 4, maxbuf, 0,
                       b0s2, b0b2, (const double*)res0, (void*)hbuf, maxbuf, 1);
    hipLaunchKernelGGL(adecomp_k, dim3(1728), b256, 0, stream, hbuf, actL, maxbuf, 1, 7448, 76, 1);

    for (int i = 0; i < 19; i++){
        const int sIn = 2*i + 1, sO = 2*i + 2, sH = 2*i + 3;
        prep(2+2*i);
        hipLaunchKernelGGL((convL<0,2>), dim3(864), b128, 0, stream,
                           actL, 7448, 76, 1, 1, Bp(2+2*i), Ep(2+2*i), 128, 4, maxbuf, sIn,
                           bs1 + i*128, bb1 + i*128, (const double*)nullptr,
                           (void*)obuf, maxbuf, sO);
        hipLaunchKernelGGL(adecomp_k, dim3(1728), b256, 0, stream, obuf, actL, maxbuf, sO, 7448, 76, 1);
        prep(3+2*i);
        hipLaunchKernelGGL((convL<1,2>), dim3(864), b128, 0, stream,
                           actL, 7448, 76, 1, 1, Bp(3+2*i), Ep(3+2*i), 128, 4, maxbuf, sO,
                           bs2 + i*128, bb2 + i*128, (const double*)hbuf,
                           (void*)hbuf, maxbuf, sH);
        if (i < 18)
            hipLaunchKernelGGL(adecomp_k, dim3(1728), b256, 0, stream, hbuf, actL, maxbuf, sH, 7448, 76, 1);
    }

    // offsets + deform (feat = hbuf, max slot 39)
    hipMemsetAsync(bigL, 0, bigLB, stream);
    hipLaunchKernelGGL(adecomp_k, dim3(1728), b256, 0, stream, hbuf, bigL, maxbuf, 39, 17280, 120, 24);
    if (fused){
        hipLaunchKernelGGL(convLo, dim3(10800), b256, 0, stream,
                           bigL, 17280, 120, 24, Bp(40), Ep(40), maxbuf, 39, offb);
        hipLaunchKernelGGL(deform_all, dim3(4320), b256, 0, stream, x, offb, dcw, out);
    } else {
        const int dils[5] = {3,6,12,18,24};
        for (int d = 0; d < 5; d++){
            prep(40+d);
            hipLaunchKernelGGL((convL<2,2>), dim3(1080), b128, 0, stream,
                               bigL, 17280, 120, 24, dils[d], Bp(40+d), Ep(40+d), 306, 10, maxbuf, 39,
                               (const float*)nullptr, (const float*)nullptr,
                               (const double*)nullptr, (void*)offb, (u64*)nullptr, 0);
            hipLaunchKernelGGL(deform_kd, dim3(864), b256, 0, stream,
                               x, offb, dcw + (size_t)d*2601, out, dils[d]);
        }
    }
}